// Round 1
// baseline (2207.001 us; speedup 1.0000x reference)
//
#include <hip/hip_runtime.h>

// MaxUnpooling2D: scatter-add inputs into zeroed (B, 256, 256, 256) fp32 output.
// B=8, per-batch input elems = 128*128*256 = 2^22, per-batch output = 2^24.

#define N_TOTAL (8 * 128 * 128 * 256)   // 2^25 input elements
#define LOG2_HWC 22                      // per-batch input element count = 2^22
#define LOG2_FLAT 24                     // per-batch output flat size = 2^24

__global__ __launch_bounds__(256) void unpool_scatter(
    const float* __restrict__ in,
    const int* __restrict__ idx,
    float* __restrict__ out,
    int n4)
{
    int t = blockIdx.x * blockDim.x + threadIdx.x;
    if (t >= n4) return;

    // 4 consecutive elements per thread; 4 | 2^22 so no batch straddle.
    const float4 v  = ((const float4*)in)[t];
    const int4  id  = ((const int4*)idx)[t];

    int e = t << 2;
    int b = e >> LOG2_HWC;
    float* base = out + ((long long)b << LOG2_FLAT);

    atomicAdd(base + id.x, v.x);
    atomicAdd(base + id.y, v.y);
    atomicAdd(base + id.z, v.z);
    atomicAdd(base + id.w, v.w);
}

extern "C" void kernel_launch(void* const* d_in, const int* in_sizes, int n_in,
                              void* d_out, int out_size, void* d_ws, size_t ws_size,
                              hipStream_t stream) {
    const float* in  = (const float*)d_in[0];
    const int*   idx = (const int*)d_in[1];
    float*       out = (float*)d_out;

    // Harness poisons d_out with 0xAA before every timed launch — zero it.
    hipMemsetAsync(d_out, 0, (size_t)out_size * sizeof(float), stream);

    int n  = in_sizes[0];        // 2^25
    int n4 = n >> 2;             // 2^23 threads
    int block = 256;
    int grid = (n4 + block - 1) / block;   // 32768 blocks
    unpool_scatter<<<grid, block, 0, stream>>>(in, idx, out, n4);
}